// Round 1
// baseline (1332.353 us; speedup 1.0000x reference)
//
#include <hip/hip_runtime.h>
#include <math.h>
#include <cstddef>

// AttentionBlock: B=4, L=2048, C=512, H=8, Dk=64
// qkv = x @ W_in + b_in          [8192, 1536], head h: q@h*192+0, k@+64, v@+128
// attn = causal-softmax(q k^T / 8) @ v   per head
// out  = attn_flat @ W_out + b_out + x   [8192, 512]

constexpr int B_SZ  = 4;
constexpr int L_SEQ = 2048;
constexpr int C_DIM = 512;
constexpr int H_N   = 8;
constexpr int DK    = 64;
constexpr int N_QKV = 1536;          // 3*H*DK
constexpr int M_ROWS = B_SZ * L_SEQ; // 8192
constexpr float SCALE = 0.125f;      // Dk^-0.5

// ---------------------------------------------------------------- SGEMM fp32
// C[M,N] = A[M,K] @ B[K,N] + bias[N] (+ resid[M,N])
template <int BM, int BN, int BK, int TM, int TN>
__global__ __launch_bounds__(256) void sgemm_bias(
    const float* __restrict__ A, const float* __restrict__ Bm,
    const float* __restrict__ bias, float* __restrict__ C,
    const float* __restrict__ resid, int M, int N, int K) {
  __shared__ float As[BM][BK + 1];
  __shared__ float Bs[BK][BN];
  const int tid = threadIdx.x;
  const int bm = blockIdx.y * BM, bn = blockIdx.x * BN;
  const int tx = tid % (BN / TN);  // 16
  const int ty = tid / (BN / TN);  // 16
  float acc[TM][TN] = {};
  for (int k0 = 0; k0 < K; k0 += BK) {
#pragma unroll
    for (int i = 0; i < (BM * BK) / 256; ++i) {
      const int idx = tid + i * 256;
      const int mrow = idx / BK, kcol = idx % BK;
      As[mrow][kcol] = A[(size_t)(bm + mrow) * K + k0 + kcol];
    }
#pragma unroll
    for (int i = 0; i < (BK * BN) / 256; ++i) {
      const int idx = tid + i * 256;
      const int krow = idx / BN, ncol = idx % BN;
      Bs[krow][ncol] = Bm[(size_t)(k0 + krow) * N + bn + ncol];
    }
    __syncthreads();
#pragma unroll
    for (int kk = 0; kk < BK; ++kk) {
      float a[TM], b[TN];
#pragma unroll
      for (int i = 0; i < TM; ++i) a[i] = As[ty * TM + i][kk];
#pragma unroll
      for (int j = 0; j < TN; ++j) b[j] = Bs[kk][tx * TN + j];
#pragma unroll
      for (int i = 0; i < TM; ++i)
#pragma unroll
        for (int j = 0; j < TN; ++j) acc[i][j] = fmaf(a[i], b[j], acc[i][j]);
    }
    __syncthreads();
  }
#pragma unroll
  for (int i = 0; i < TM; ++i) {
    const int row = bm + ty * TM + i;
#pragma unroll
    for (int j = 0; j < TN; ++j) {
      const int col = bn + tx * TN + j;
      float v = acc[i][j] + bias[col];
      if (resid) v += resid[(size_t)row * N + col];
      C[(size_t)row * N + col] = v;
    }
  }
}

// ------------------------------------------------------- causal flash (fp32)
// grid (L/64, H, B), block 256. Thread (r=tid>>2, quad=tid&3) owns Q-row
// qt*64+r, d-slice [quad*16, quad*16+16). Full 64-wide score row is obtained
// by quad-reduction (shfl width 4); softmax state fully in registers.
__global__ __launch_bounds__(256) void flash_fp32(
    const float* __restrict__ qkv, float* __restrict__ attn_out) {
  constexpr int BQ = 64, BJ = 64;
  __shared__ float Ks[BJ][DK];
  __shared__ float Vs[BJ][DK];
  const int qt = blockIdx.x, h = blockIdx.y, b = blockIdx.z;
  const int tid = threadIdx.x;
  const int r = tid >> 2, quad = tid & 3, d0 = quad * 16;
  const size_t bbase = (size_t)b * L_SEQ * N_QKV;
  const int i_row = qt * BQ + r;

  float qreg[16];
  {
    const float* qrow = qkv + bbase + (size_t)i_row * N_QKV + h * 192 + d0;
#pragma unroll
    for (int t = 0; t < 16; t += 4) {
      const float4 v4 = *reinterpret_cast<const float4*>(qrow + t);
      qreg[t] = v4.x; qreg[t + 1] = v4.y; qreg[t + 2] = v4.z; qreg[t + 3] = v4.w;
    }
  }

  float m = -INFINITY, l = 0.f;
  float o[16];
#pragma unroll
  for (int t = 0; t < 16; ++t) o[t] = 0.f;

  for (int jt = 0; jt <= qt; ++jt) {
    __syncthreads();  // previous tile fully consumed
#pragma unroll
    for (int it = 0; it < 4; ++it) {
      const int idx = tid + it * 256;       // float4 index into 64x64 tile
      const int row = idx >> 4;             // 16 float4 per row
      const int col = (idx & 15) << 2;
      const float* src = qkv + bbase + (size_t)(jt * BJ + row) * N_QKV + h * 192;
      *reinterpret_cast<float4*>(&Ks[row][col]) =
          *reinterpret_cast<const float4*>(src + 64 + col);
      *reinterpret_cast<float4*>(&Vs[row][col]) =
          *reinterpret_cast<const float4*>(src + 128 + col);
    }
    __syncthreads();

    // partial dots over this thread's 16 d's, all 64 j's
    float p[BJ];
#pragma unroll
    for (int j = 0; j < BJ; ++j) {
      const float* krow = &Ks[j][d0];
      float acc = 0.f;
#pragma unroll
      for (int t = 0; t < 16; ++t) acc = fmaf(qreg[t], krow[t], acc);
      p[j] = acc;
    }
    // quad-reduce to full dot, scale, causal mask
#pragma unroll
    for (int j = 0; j < BJ; ++j) {
      p[j] += __shfl_xor(p[j], 1, 4);
      p[j] += __shfl_xor(p[j], 2, 4);
      p[j] *= SCALE;
      if (jt * BJ + j > i_row) p[j] = -INFINITY;
    }
    float pm = p[0];
#pragma unroll
    for (int j = 1; j < BJ; ++j) pm = fmaxf(pm, p[j]);
    const float mnew = fmaxf(m, pm);
    const float corr = __expf(m - mnew);  // exp(-inf)=0 on first tile
    float ls = 0.f;
#pragma unroll
    for (int j = 0; j < BJ; ++j) {
      p[j] = __expf(p[j] - mnew);
      ls += p[j];
    }
    l = l * corr + ls;
#pragma unroll
    for (int t = 0; t < 16; ++t) o[t] *= corr;
    m = mnew;
#pragma unroll
    for (int j = 0; j < BJ; ++j) {
      const float pj = p[j];
      const float* vrow = &Vs[j][d0];
#pragma unroll
      for (int t = 0; t < 16; ++t) o[t] = fmaf(pj, vrow[t], o[t]);
    }
  }

  const float inv = 1.f / l;
  float* orow = attn_out + ((size_t)b * L_SEQ + i_row) * (H_N * DK) + h * DK + d0;
#pragma unroll
  for (int t = 0; t < 16; ++t) orow[t] = o[t] * inv;
}

// ------------------------------------------------------------------- launch
extern "C" void kernel_launch(void* const* d_in, const int* in_sizes, int n_in,
                              void* d_out, int out_size, void* d_ws,
                              size_t ws_size, hipStream_t stream) {
  const float* x     = (const float*)d_in[0];
  const float* W_in  = (const float*)d_in[1];
  const float* b_in  = (const float*)d_in[2];
  const float* W_out = (const float*)d_in[3];
  const float* b_out = (const float*)d_in[4];
  float* out = (float*)d_out;

  // ws layout: qkv [8192,1536] fp32 (50.3MB) | attn [8192,512] fp32 (16.8MB)
  float* qkv  = (float*)d_ws;
  float* attn = qkv + (size_t)M_ROWS * N_QKV;

  // 1) qkv = x @ W_in + b_in
  sgemm_bias<64, 64, 16, 4, 4><<<dim3(N_QKV / 64, M_ROWS / 64), 256, 0, stream>>>(
      x, W_in, b_in, qkv, nullptr, M_ROWS, N_QKV, C_DIM);
  // 2) causal flash attention per (b,h)
  flash_fp32<<<dim3(L_SEQ / 64, H_N, B_SZ), 256, 0, stream>>>(qkv, attn);
  // 3) out = attn @ W_out + b_out + x
  sgemm_bias<64, 64, 16, 4, 4><<<dim3(C_DIM / 64, M_ROWS / 64), 256, 0, stream>>>(
      attn, W_out, b_out, out, x, M_ROWS, C_DIM, C_DIM);
}

// Round 2
// 484.104 us; speedup vs baseline: 2.7522x; 2.7522x over previous
//
#include <hip/hip_runtime.h>
#include <math.h>
#include <cstddef>

// AttentionBlock: B=4, L=2048, C=512, H=8, Dk=64
// qkv = x @ W_in + b_in ; per head: causal-softmax(q k^T/8) @ v ; @ W_out + b_out + x

constexpr int B_SZ  = 4;
constexpr int L_SEQ = 2048;
constexpr int C_DIM = 512;
constexpr int H_N   = 8;
constexpr int DK    = 64;
constexpr int N_QKV = 1536;
constexpr int M_ROWS = B_SZ * L_SEQ; // 8192
constexpr float SCALE = 0.125f;

typedef __attribute__((ext_vector_type(4))) float f32x4;
typedef __attribute__((ext_vector_type(8))) short bf16x8;

static __device__ inline ushort f2bf(float f) {
  unsigned u = __builtin_bit_cast(unsigned, f);
  u += 0x7fffu + ((u >> 16) & 1u);
  return (ushort)(u >> 16);
}

// ------------------------------------------------- GEMM1: qkv, bf16 epilogue
// C[8192,1536] = x @ W_in + b_in, written as bf16 Q,K [B*H,L,64], Vt [B*H,64,L]
__global__ __launch_bounds__(256) void qkv_gemm(
    const float* __restrict__ A, const float* __restrict__ Bm,
    const float* __restrict__ bias, ushort* __restrict__ Qo,
    ushort* __restrict__ Ko, ushort* __restrict__ Vto) {
  constexpr int BM = 64, BN = 64, BK = 16, TM = 4, TN = 4;
  constexpr int M = M_ROWS, N = N_QKV, K = C_DIM;
  __shared__ float As[BM][BK + 1];
  __shared__ float Bs[BK][BN];
  __shared__ ushort Tb[64][68];  // V transpose buffer (pad->8B align, ~2-way)
  const int tid = threadIdx.x;
  const int bm = blockIdx.y * BM, bn = blockIdx.x * BN;
  const int tx = tid % (BN / TN), ty = tid / (BN / TN);
  float acc[TM][TN] = {};
  for (int k0 = 0; k0 < K; k0 += BK) {
#pragma unroll
    for (int i = 0; i < (BM * BK) / 256; ++i) {
      const int idx = tid + i * 256;
      As[idx / BK][idx % BK] = A[(size_t)(bm + idx / BK) * K + k0 + idx % BK];
    }
#pragma unroll
    for (int i = 0; i < (BK * BN) / 256; ++i) {
      const int idx = tid + i * 256;
      Bs[idx / BN][idx % BN] = Bm[(size_t)(k0 + idx / BN) * N + bn + idx % BN];
    }
    __syncthreads();
#pragma unroll
    for (int kk = 0; kk < BK; ++kk) {
      float a[TM], b[TN];
#pragma unroll
      for (int i = 0; i < TM; ++i) a[i] = As[ty * TM + i][kk];
#pragma unroll
      for (int j = 0; j < TN; ++j) b[j] = Bs[kk][tx * TN + j];
#pragma unroll
      for (int i = 0; i < TM; ++i)
#pragma unroll
        for (int j = 0; j < TN; ++j) acc[i][j] = fmaf(a[i], b[j], acc[i][j]);
    }
    __syncthreads();
  }
#pragma unroll
  for (int i = 0; i < TM; ++i)
#pragma unroll
    for (int j = 0; j < TN; ++j) acc[i][j] += bias[bn + tx * TN + j];

  const int type = (bn % 192) / 64;  // 0:q 1:k 2:v
  const int h = bn / 192;
  const int b = bm >> 11;            // 2048 rows per batch
  const int l0 = bm & 2047;
  if (type < 2) {
    ushort* dst = (type == 0) ? Qo : Ko;
#pragma unroll
    for (int i = 0; i < TM; ++i) {
      const int l = l0 + ty * TM + i;
      ushort4 pk;
      pk.x = f2bf(acc[i][0]); pk.y = f2bf(acc[i][1]);
      pk.z = f2bf(acc[i][2]); pk.w = f2bf(acc[i][3]);
      *reinterpret_cast<ushort4*>(
          dst + ((size_t)(b * H_N + h) * L_SEQ + l) * DK + tx * TN) = pk;
    }
  } else {
    __syncthreads();
#pragma unroll
    for (int i = 0; i < TM; ++i)
#pragma unroll
      for (int j = 0; j < TN; ++j)
        Tb[tx * TN + j][ty * TM + i] = f2bf(acc[i][j]);
    __syncthreads();
#pragma unroll
    for (int rr = 0; rr < 4; ++rr) {
      const int idx = tid + rr * 256;
      const int d = idx >> 4, lseg = (idx & 15) * 4;
      ushort4 v = *reinterpret_cast<ushort4*>(&Tb[d][lseg]);
      *reinterpret_cast<ushort4*>(
          Vto + ((size_t)(b * H_N + h) * DK + d) * L_SEQ + l0 + lseg) = v;
    }
  }
}

// ---------------------------------------------- attention core (bf16 MFMA)
// grid (L/64, H, B), 256 thr = 4 waves. Wave w: q rows qt*64+16w..+15.
// A-frag: lane row=l&15, k=(l>>4)*8+[0..7]. C/D: col=l&15, row=4*(l>>4)+reg.
__global__ __launch_bounds__(256) void attn_mfma(
    const ushort* __restrict__ Q, const ushort* __restrict__ K,
    const ushort* __restrict__ Vt, float* __restrict__ attn_out) {
  __shared__ ushort P_lds[4][16][72];  // per-wave, stride 144B (16B-aligned)
  const int qt = blockIdx.x, h = blockIdx.y, b = blockIdx.z;
  const int tid = threadIdx.x;
  const int w = tid >> 6, lane = tid & 63;
  const int c = lane & 15, g = lane >> 4;
  const int bh = b * H_N + h;
  const size_t qk_base = (size_t)bh * L_SEQ * DK;
  const size_t vt_base = (size_t)bh * DK * L_SEQ;
  const int q0 = qt * 64 + w * 16;

  bf16x8 qA[2];
  {
    const ushort* qp = Q + qk_base + (size_t)(q0 + c) * DK + g * 8;
    qA[0] = *reinterpret_cast<const bf16x8*>(qp);
    qA[1] = *reinterpret_cast<const bf16x8*>(qp + 32);
  }

  f32x4 O[4] = {};                       // O[q=4g+r][d=t*16+c]
  float mrow[4] = {-INFINITY, -INFINITY, -INFINITY, -INFINITY};
  float lrow[4] = {};
  const f32x4 zero4 = {0.f, 0.f, 0.f, 0.f};

  for (int jt = 0; jt <= qt; ++jt) {
    const int j0 = jt * 64;
    // ---- QK^T: S[q][j], 4 n-tiles x 2 k-chunks
    f32x4 S[4];
#pragma unroll
    for (int n = 0; n < 4; ++n) {
      const ushort* kp = K + qk_base + (size_t)(j0 + n * 16 + c) * DK + g * 8;
      bf16x8 kb0 = *reinterpret_cast<const bf16x8*>(kp);
      bf16x8 kb1 = *reinterpret_cast<const bf16x8*>(kp + 32);
      S[n] = __builtin_amdgcn_mfma_f32_16x16x32_bf16(qA[0], kb0, zero4, 0, 0, 0);
      S[n] = __builtin_amdgcn_mfma_f32_16x16x32_bf16(qA[1], kb1, S[n], 0, 0, 0);
    }
    // ---- issue V-frag loads early (hide L2 latency under softmax VALU)
    bf16x8 vb[4][2];
#pragma unroll
    for (int t = 0; t < 4; ++t) {
      const ushort* vp = Vt + vt_base + (size_t)(t * 16 + c) * L_SEQ + j0 + g * 8;
      vb[t][0] = *reinterpret_cast<const bf16x8*>(vp);
      vb[t][1] = *reinterpret_cast<const bf16x8*>(vp + 32);
    }
    // ---- softmax (row q = 4g+r lives in 16-lane segment; reduce over c)
    const bool diag = (jt == qt);
    float corr[4];
#pragma unroll
    for (int n = 0; n < 4; ++n)
#pragma unroll
      for (int r = 0; r < 4; ++r) {
        float v = S[n][r] * SCALE;
        if (diag && (j0 + n * 16 + c) > (q0 + 4 * g + r)) v = -INFINITY;
        S[n][r] = v;
      }
#pragma unroll
    for (int r = 0; r < 4; ++r) {
      float pm = fmaxf(fmaxf(S[0][r], S[1][r]), fmaxf(S[2][r], S[3][r]));
      pm = fmaxf(pm, __shfl_xor(pm, 1, 16));
      pm = fmaxf(pm, __shfl_xor(pm, 2, 16));
      pm = fmaxf(pm, __shfl_xor(pm, 4, 16));
      pm = fmaxf(pm, __shfl_xor(pm, 8, 16));
      const float mnew = fmaxf(mrow[r], pm);
      corr[r] = __expf(mrow[r] - mnew);
      float s = 0.f;
#pragma unroll
      for (int n = 0; n < 4; ++n) {
        const float p = __expf(S[n][r] - mnew);
        S[n][r] = p;
        s += p;
      }
      s += __shfl_xor(s, 1, 16);
      s += __shfl_xor(s, 2, 16);
      s += __shfl_xor(s, 4, 16);
      s += __shfl_xor(s, 8, 16);
      lrow[r] = lrow[r] * corr[r] + s;
      mrow[r] = mnew;
    }
    // ---- P -> bf16 via per-wave LDS re-layout into PV A-frag
#pragma unroll
    for (int n = 0; n < 4; ++n)
#pragma unroll
      for (int r = 0; r < 4; ++r)
        P_lds[w][4 * g + r][n * 16 + c] = f2bf(S[n][r]);
    bf16x8 pA0 = *reinterpret_cast<const bf16x8*>(&P_lds[w][c][g * 8]);
    bf16x8 pA1 = *reinterpret_cast<const bf16x8*>(&P_lds[w][c][32 + g * 8]);
    // ---- rescale O, then PV
#pragma unroll
    for (int t = 0; t < 4; ++t)
#pragma unroll
      for (int r = 0; r < 4; ++r) O[t][r] *= corr[r];
#pragma unroll
    for (int t = 0; t < 4; ++t) {
      O[t] = __builtin_amdgcn_mfma_f32_16x16x32_bf16(pA0, vb[t][0], O[t], 0, 0, 0);
      O[t] = __builtin_amdgcn_mfma_f32_16x16x32_bf16(pA1, vb[t][1], O[t], 0, 0, 0);
    }
  }
  float inv[4];
#pragma unroll
  for (int r = 0; r < 4; ++r) inv[r] = 1.f / lrow[r];
#pragma unroll
  for (int t = 0; t < 4; ++t)
#pragma unroll
    for (int r = 0; r < 4; ++r)
      attn_out[((size_t)b * L_SEQ + q0 + 4 * g + r) * C_DIM + h * DK + t * 16 + c] =
          O[t][r] * inv[r];
}

// ---------------------------------------------------------------- SGEMM fp32
template <int BM, int BN, int BK, int TM, int TN>
__global__ __launch_bounds__(256) void sgemm_bias(
    const float* __restrict__ A, const float* __restrict__ Bm,
    const float* __restrict__ bias, float* __restrict__ C,
    const float* __restrict__ resid, int M, int N, int K) {
  __shared__ float As[BM][BK + 1];
  __shared__ float Bs[BK][BN];
  const int tid = threadIdx.x;
  const int bm = blockIdx.y * BM, bn = blockIdx.x * BN;
  const int tx = tid % (BN / TN), ty = tid / (BN / TN);
  float acc[TM][TN] = {};
  for (int k0 = 0; k0 < K; k0 += BK) {
#pragma unroll
    for (int i = 0; i < (BM * BK) / 256; ++i) {
      const int idx = tid + i * 256;
      As[idx / BK][idx % BK] = A[(size_t)(bm + idx / BK) * K + k0 + idx % BK];
    }
#pragma unroll
    for (int i = 0; i < (BK * BN) / 256; ++i) {
      const int idx = tid + i * 256;
      Bs[idx / BN][idx % BN] = Bm[(size_t)(k0 + idx / BN) * N + bn + idx % BN];
    }
    __syncthreads();
#pragma unroll
    for (int kk = 0; kk < BK; ++kk) {
      float a[TM], b[TN];
#pragma unroll
      for (int i = 0; i < TM; ++i) a[i] = As[ty * TM + i][kk];
#pragma unroll
      for (int j = 0; j < TN; ++j) b[j] = Bs[kk][tx * TN + j];
#pragma unroll
      for (int i = 0; i < TM; ++i)
#pragma unroll
        for (int j = 0; j < TN; ++j) acc[i][j] = fmaf(a[i], b[j], acc[i][j]);
    }
    __syncthreads();
  }
#pragma unroll
  for (int i = 0; i < TM; ++i) {
    const int row = bm + ty * TM + i;
#pragma unroll
    for (int j = 0; j < TN; ++j) {
      const int col = bn + tx * TN + j;
      float v = acc[i][j] + bias[col];
      if (resid) v += resid[(size_t)row * N + col];
      C[(size_t)row * N + col] = v;
    }
  }
}

// ------------------------------------------------------------------- launch
extern "C" void kernel_launch(void* const* d_in, const int* in_sizes, int n_in,
                              void* d_out, int out_size, void* d_ws,
                              size_t ws_size, hipStream_t stream) {
  const float* x     = (const float*)d_in[0];
  const float* W_in  = (const float*)d_in[1];
  const float* b_in  = (const float*)d_in[2];
  const float* W_out = (const float*)d_in[3];
  const float* b_out = (const float*)d_in[4];
  float* out = (float*)d_out;

  // ws: Q bf16 8.4MB | K bf16 8.4MB | Vt bf16 8.4MB | attn fp32 16.8MB
  ushort* Qo  = (ushort*)d_ws;
  ushort* Ko  = Qo + (size_t)M_ROWS * C_DIM;
  ushort* Vto = Ko + (size_t)M_ROWS * C_DIM;
  float* attn = (float*)(Vto + (size_t)M_ROWS * C_DIM);

  qkv_gemm<<<dim3(N_QKV / 64, M_ROWS / 64), 256, 0, stream>>>(
      x, W_in, b_in, Qo, Ko, Vto);
  attn_mfma<<<dim3(L_SEQ / 64, H_N, B_SZ), 256, 0, stream>>>(Qo, Ko, Vto, attn);
  sgemm_bias<64, 64, 16, 4, 4><<<dim3(C_DIM / 64, M_ROWS / 64), 256, 0, stream>>>(
      attn, W_out, b_out, out, x, M_ROWS, C_DIM, C_DIM);
}

// Round 3
// 282.091 us; speedup vs baseline: 4.7231x; 1.7161x over previous
//
#include <hip/hip_runtime.h>
#include <math.h>
#include <cstddef>

// AttentionBlock: B=4, L=2048, C=512, H=8, Dk=64
// qkv = x @ W_in + b_in ; per head: causal-softmax(q k^T/8) @ v ; @ W_out + b_out + x

constexpr int B_SZ  = 4;
constexpr int L_SEQ = 2048;
constexpr int C_DIM = 512;
constexpr int H_N   = 8;
constexpr int DK    = 64;
constexpr int N_QKV = 1536;
constexpr int M_ROWS = B_SZ * L_SEQ; // 8192
constexpr float SCALE = 0.125f;

typedef __attribute__((ext_vector_type(4))) float f32x4;
typedef __attribute__((ext_vector_type(8))) short bf16x8;

static __device__ inline ushort f2bf(float f) {
  unsigned u = __builtin_bit_cast(unsigned, f);
  u += 0x7fffu + ((u >> 16) & 1u);
  return (ushort)(u >> 16);
}

typedef __attribute__((address_space(1))) const unsigned int* gas1_t;
typedef __attribute__((address_space(3))) unsigned int* las3_t;
static __device__ inline void gload_lds16(const void* g, void* l) {
  __builtin_amdgcn_global_load_lds((gas1_t)g, (las3_t)l, 16, 0, 0);
}

// ----------------------------------------------------------- prep kernels
__global__ __launch_bounds__(256) void convert_bf16(
    const float* __restrict__ src, ushort* __restrict__ dst, int n4) {
  const int i = blockIdx.x * 256 + threadIdx.x;
  if (i < n4) {
    const float4 v = reinterpret_cast<const float4*>(src)[i];
    ushort4 o;
    o.x = f2bf(v.x); o.y = f2bf(v.y); o.z = f2bf(v.z); o.w = f2bf(v.w);
    reinterpret_cast<ushort4*>(dst)[i] = o;
  }
}

// dst[c][r] = bf16(src[r][c]); src R x C fp32, dst C x R bf16. 64x64 tiles.
__global__ __launch_bounds__(256) void transpose_bf16(
    const float* __restrict__ src, ushort* __restrict__ dst, int R, int C) {
  __shared__ ushort T[64][65];
  const int c0 = blockIdx.x * 64, r0 = blockIdx.y * 64;
#pragma unroll
  for (int p = 0; p < 16; ++p) {
    const int idx = threadIdx.x + p * 256;
    const int r = idx >> 6, c = idx & 63;
    T[r][c] = f2bf(src[(size_t)(r0 + r) * C + c0 + c]);
  }
  __syncthreads();
#pragma unroll
  for (int p = 0; p < 16; ++p) {
    const int idx = threadIdx.x + p * 256;
    const int r = idx >> 6, c = idx & 63;
    dst[(size_t)(c0 + r) * R + r0 + c] = T[c][r];
  }
}

// -------------------------------------------------- bf16 MFMA GEMM 128x128
// A [M x K] bf16 row-major, Bt [N x K] bf16 (B transposed). BK=32, 4 waves,
// each wave 64x64 via 4x4 frags of 16x16x32. EPI 0: qkv split; EPI 1: out.
template <int EPI>
__global__ __launch_bounds__(256) void gemm_bf16(
    const ushort* __restrict__ A, const ushort* __restrict__ Bt,
    const float* __restrict__ bias, ushort* __restrict__ Qo,
    ushort* __restrict__ Ko, ushort* __restrict__ Vto,
    float* __restrict__ outF, const float* __restrict__ resid,
    int N, int K) {
  __shared__ ushort Al[128 * 32];
  __shared__ ushort Bl[128 * 32];
  const int tid = threadIdx.x;
  const int w = tid >> 6, l = tid & 63;
  const int cc = l & 15, gg = l >> 4;
  const int bm = blockIdx.y * 128, bn = blockIdx.x * 128;
  const int wr = w >> 1, wc = w & 1;
  f32x4 acc[4][4] = {};

  for (int k0 = 0; k0 < K; k0 += 32) {
    // stage A,B tiles: chunk c covers LDS bytes c*16; row=c/4, kcol=(c&3)*8
#pragma unroll
    for (int q = 0; q < 2; ++q) {
      const int cbase = q * 256 + w * 64;
      const int c = cbase + l;
      gload_lds16(A + (size_t)(bm + (c >> 2)) * K + k0 + (c & 3) * 8,
                  &Al[cbase * 8]);
      gload_lds16(Bt + (size_t)(bn + (c >> 2)) * K + k0 + (c & 3) * 8,
                  &Bl[cbase * 8]);
    }
    __syncthreads();  // vmcnt drain + join
    bf16x8 aF[4], bF[4];
#pragma unroll
    for (int i = 0; i < 4; ++i)
      aF[i] = *reinterpret_cast<const bf16x8*>(
          &Al[(wr * 64 + i * 16 + cc) * 32 + gg * 8]);
#pragma unroll
    for (int j = 0; j < 4; ++j)
      bF[j] = *reinterpret_cast<const bf16x8*>(
          &Bl[(wc * 64 + j * 16 + cc) * 32 + gg * 8]);
#pragma unroll
    for (int i = 0; i < 4; ++i)
#pragma unroll
      for (int j = 0; j < 4; ++j)
        acc[i][j] = __builtin_amdgcn_mfma_f32_16x16x32_bf16(aF[i], bF[j],
                                                            acc[i][j], 0, 0, 0);
    __syncthreads();  // all reads done before next stage
  }

  if (EPI == 0) {
    // C/D: col=cc, rows 4*gg+r. Split into Q,K [BH,L,64] and Vt [BH,64,L].
#pragma unroll
    for (int j = 0; j < 4; ++j) {
      const int colbase = bn + wc * 64 + j * 16;
      const int h = colbase / 192, rem = colbase % 192;
      const int type = rem / 64, d = (rem % 64) + cc;
      const float bv = bias[colbase + cc];
#pragma unroll
      for (int i = 0; i < 4; ++i) {
        const int rowbase = bm + wr * 64 + i * 16 + 4 * gg;
        const int b = rowbase >> 11, ll = rowbase & 2047;
        if (type < 2) {
          ushort* dst = (type == 0) ? Qo : Ko;
#pragma unroll
          for (int r = 0; r < 4; ++r)
            dst[((size_t)(b * H_N + h) * L_SEQ + ll + r) * DK + d] =
                f2bf(acc[i][j][r] + bv);
        } else {
          ushort4 pk;
          pk.x = f2bf(acc[i][j][0] + bv);
          pk.y = f2bf(acc[i][j][1] + bv);
          pk.z = f2bf(acc[i][j][2] + bv);
          pk.w = f2bf(acc[i][j][3] + bv);
          *reinterpret_cast<ushort4*>(
              &Vto[((size_t)(b * H_N + h) * DK + d) * L_SEQ + ll]) = pk;
        }
      }
    }
  } else {
#pragma unroll
    for (int j = 0; j < 4; ++j) {
      const int col = bn + wc * 64 + j * 16 + cc;
      const float bv = bias[col];
#pragma unroll
      for (int i = 0; i < 4; ++i) {
        const int rowbase = bm + wr * 64 + i * 16 + 4 * gg;
#pragma unroll
        for (int r = 0; r < 4; ++r) {
          const size_t off = (size_t)(rowbase + r) * N + col;
          outF[off] = acc[i][j][r] + bv + resid[off];
        }
      }
    }
  }
}

// ---------------------------------------------- attention core (bf16 MFMA)
// grid (32, H, B), 256 thr = 4 waves; qt reversed for dispatch load balance.
__global__ __launch_bounds__(256) void attn_mfma(
    const ushort* __restrict__ Q, const ushort* __restrict__ K,
    const ushort* __restrict__ Vt, ushort* __restrict__ attn_out) {
  __shared__ ushort P_lds[4][16][72];
  const int qt = gridDim.x - 1 - blockIdx.x;  // heavy blocks first
  const int h = blockIdx.y, b = blockIdx.z;
  const int tid = threadIdx.x;
  const int w = tid >> 6, lane = tid & 63;
  const int c = lane & 15, g = lane >> 4;
  const int bh = b * H_N + h;
  const size_t qk_base = (size_t)bh * L_SEQ * DK;
  const size_t vt_base = (size_t)bh * DK * L_SEQ;
  const int q0 = qt * 64 + w * 16;

  bf16x8 qA[2];
  {
    const ushort* qp = Q + qk_base + (size_t)(q0 + c) * DK + g * 8;
    qA[0] = *reinterpret_cast<const bf16x8*>(qp);
    qA[1] = *reinterpret_cast<const bf16x8*>(qp + 32);
  }

  f32x4 O[4] = {};
  float mrow[4] = {-INFINITY, -INFINITY, -INFINITY, -INFINITY};
  float lrow[4] = {};
  const f32x4 zero4 = {0.f, 0.f, 0.f, 0.f};

  for (int jt = 0; jt <= qt; ++jt) {
    const int j0 = jt * 64;
    f32x4 S[4];
#pragma unroll
    for (int n = 0; n < 4; ++n) {
      const ushort* kp = K + qk_base + (size_t)(j0 + n * 16 + c) * DK + g * 8;
      bf16x8 kb0 = *reinterpret_cast<const bf16x8*>(kp);
      bf16x8 kb1 = *reinterpret_cast<const bf16x8*>(kp + 32);
      S[n] = __builtin_amdgcn_mfma_f32_16x16x32_bf16(qA[0], kb0, zero4, 0, 0, 0);
      S[n] = __builtin_amdgcn_mfma_f32_16x16x32_bf16(qA[1], kb1, S[n], 0, 0, 0);
    }
    bf16x8 vb[4][2];
#pragma unroll
    for (int t = 0; t < 4; ++t) {
      const ushort* vp = Vt + vt_base + (size_t)(t * 16 + c) * L_SEQ + j0 + g * 8;
      vb[t][0] = *reinterpret_cast<const bf16x8*>(vp);
      vb[t][1] = *reinterpret_cast<const bf16x8*>(vp + 32);
    }
    const bool diag = (jt == qt);
    float corr[4];
#pragma unroll
    for (int n = 0; n < 4; ++n)
#pragma unroll
      for (int r = 0; r < 4; ++r) {
        float v = S[n][r] * SCALE;
        if (diag && (j0 + n * 16 + c) > (q0 + 4 * g + r)) v = -INFINITY;
        S[n][r] = v;
      }
#pragma unroll
    for (int r = 0; r < 4; ++r) {
      float pm = fmaxf(fmaxf(S[0][r], S[1][r]), fmaxf(S[2][r], S[3][r]));
      pm = fmaxf(pm, __shfl_xor(pm, 1, 16));
      pm = fmaxf(pm, __shfl_xor(pm, 2, 16));
      pm = fmaxf(pm, __shfl_xor(pm, 4, 16));
      pm = fmaxf(pm, __shfl_xor(pm, 8, 16));
      const float mnew = fmaxf(mrow[r], pm);
      corr[r] = __expf(mrow[r] - mnew);
      float s = 0.f;
#pragma unroll
      for (int n = 0; n < 4; ++n) {
        const float p = __expf(S[n][r] - mnew);
        S[n][r] = p;
        s += p;
      }
      s += __shfl_xor(s, 1, 16);
      s += __shfl_xor(s, 2, 16);
      s += __shfl_xor(s, 4, 16);
      s += __shfl_xor(s, 8, 16);
      lrow[r] = lrow[r] * corr[r] + s;
      mrow[r] = mnew;
    }
#pragma unroll
    for (int n = 0; n < 4; ++n)
#pragma unroll
      for (int r = 0; r < 4; ++r)
        P_lds[w][4 * g + r][n * 16 + c] = f2bf(S[n][r]);
    bf16x8 pA0 = *reinterpret_cast<const bf16x8*>(&P_lds[w][c][g * 8]);
    bf16x8 pA1 = *reinterpret_cast<const bf16x8*>(&P_lds[w][c][32 + g * 8]);
#pragma unroll
    for (int t = 0; t < 4; ++t)
#pragma unroll
      for (int r = 0; r < 4; ++r) O[t][r] *= corr[r];
#pragma unroll
    for (int t = 0; t < 4; ++t) {
      O[t] = __builtin_amdgcn_mfma_f32_16x16x32_bf16(pA0, vb[t][0], O[t], 0, 0, 0);
      O[t] = __builtin_amdgcn_mfma_f32_16x16x32_bf16(pA1, vb[t][1], O[t], 0, 0, 0);
    }
  }
  float inv[4];
#pragma unroll
  for (int r = 0; r < 4; ++r) inv[r] = 1.f / lrow[r];
#pragma unroll
  for (int t = 0; t < 4; ++t)
#pragma unroll
    for (int r = 0; r < 4; ++r)
      attn_out[((size_t)b * L_SEQ + q0 + 4 * g + r) * C_DIM + h * DK + t * 16 + c] =
          f2bf(O[t][r] * inv[r]);
}

// ------------------------------------------------------------------- launch
extern "C" void kernel_launch(void* const* d_in, const int* in_sizes, int n_in,
                              void* d_out, int out_size, void* d_ws,
                              size_t ws_size, hipStream_t stream) {
  const float* x     = (const float*)d_in[0];
  const float* W_in  = (const float*)d_in[1];
  const float* b_in  = (const float*)d_in[2];
  const float* W_out = (const float*)d_in[3];
  const float* b_out = (const float*)d_in[4];
  float* out = (float*)d_out;

  ushort* xbf   = (ushort*)d_ws;                       // 8192x512
  ushort* WinT  = xbf + (size_t)M_ROWS * C_DIM;        // 1536x512
  ushort* WoutT = WinT + (size_t)N_QKV * C_DIM;        // 512x512
  ushort* Qo    = WoutT + (size_t)C_DIM * C_DIM;       // [BH,L,64]
  ushort* Ko    = Qo + (size_t)M_ROWS * C_DIM;
  ushort* Vto   = Ko + (size_t)M_ROWS * C_DIM;         // [BH,64,L]
  ushort* attnb = Vto + (size_t)M_ROWS * C_DIM;        // [8192,512]

  convert_bf16<<<(M_ROWS * C_DIM / 4 + 255) / 256, 256, 0, stream>>>(
      x, xbf, M_ROWS * C_DIM / 4);
  transpose_bf16<<<dim3(N_QKV / 64, C_DIM / 64), 256, 0, stream>>>(
      W_in, WinT, C_DIM, N_QKV);
  transpose_bf16<<<dim3(C_DIM / 64, C_DIM / 64), 256, 0, stream>>>(
      W_out, WoutT, C_DIM, C_DIM);

  gemm_bf16<0><<<dim3(N_QKV / 128, M_ROWS / 128), 256, 0, stream>>>(
      xbf, WinT, b_in, Qo, Ko, Vto, nullptr, nullptr, N_QKV, C_DIM);
  attn_mfma<<<dim3(L_SEQ / 64, H_N, B_SZ), 256, 0, stream>>>(Qo, Ko, Vto, attnb);
  gemm_bf16<1><<<dim3(C_DIM / 128, M_ROWS / 128), 256, 0, stream>>>(
      attnb, WoutT, b_out, nullptr, nullptr, nullptr, out, x, C_DIM, C_DIM);
}

// Round 4
// 178.613 us; speedup vs baseline: 7.4595x; 1.5793x over previous
//
#include <hip/hip_runtime.h>
#include <math.h>
#include <cstddef>

// AttentionBlock: B=4, L=2048, C=512, H=8, Dk=64
// qkv = x @ W_in + b_in ; per head: causal-softmax(q k^T/8) @ v ; @ W_out + b_out + x

constexpr int B_SZ  = 4;
constexpr int L_SEQ = 2048;
constexpr int C_DIM = 512;
constexpr int H_N   = 8;
constexpr int DK    = 64;
constexpr int N_QKV = 1536;
constexpr int M_ROWS = B_SZ * L_SEQ; // 8192
constexpr float SCALE = 0.125f;

typedef __attribute__((ext_vector_type(4))) float f32x4;
typedef __attribute__((ext_vector_type(8))) short bf16x8;

static __device__ inline ushort f2bf(float f) {
  unsigned u = __builtin_bit_cast(unsigned, f);
  u += 0x7fffu + ((u >> 16) & 1u);
  return (ushort)(u >> 16);
}

typedef __attribute__((address_space(1))) const unsigned int* gas1_t;
typedef __attribute__((address_space(3))) unsigned int* las3_t;
static __device__ inline void gload_lds16(const void* g, void* l) {
  __builtin_amdgcn_global_load_lds((gas1_t)g, (las3_t)l, 16, 0, 0);
}

// ----------------------------------------------------------- prep kernels
__global__ __launch_bounds__(256) void convert_bf16(
    const float* __restrict__ src, ushort* __restrict__ dst, int n4) {
  const int i = blockIdx.x * 256 + threadIdx.x;
  if (i < n4) {
    const float4 v = reinterpret_cast<const float4*>(src)[i];
    ushort4 o;
    o.x = f2bf(v.x); o.y = f2bf(v.y); o.z = f2bf(v.z); o.w = f2bf(v.w);
    reinterpret_cast<ushort4*>(dst)[i] = o;
  }
}

// dst[c][r] = bf16(src[r][c]); src R x C fp32, dst C x R bf16. 64x64 tiles.
__global__ __launch_bounds__(256) void transpose_bf16(
    const float* __restrict__ src, ushort* __restrict__ dst, int R, int C) {
  __shared__ ushort T[64][65];
  const int c0 = blockIdx.x * 64, r0 = blockIdx.y * 64;
#pragma unroll
  for (int p = 0; p < 16; ++p) {
    const int idx = threadIdx.x + p * 256;
    const int r = idx >> 6, c = idx & 63;
    T[r][c] = f2bf(src[(size_t)(r0 + r) * C + c0 + c]);
  }
  __syncthreads();
#pragma unroll
  for (int p = 0; p < 16; ++p) {
    const int idx = threadIdx.x + p * 256;
    const int r = idx >> 6, c = idx & 63;
    dst[(size_t)(c0 + r) * R + r0 + c] = T[c][r];
  }
}

// -------------------------------------------------- bf16 MFMA GEMM 128x128
template <int EPI>
__global__ __launch_bounds__(256) void gemm_bf16(
    const ushort* __restrict__ A, const ushort* __restrict__ Bt,
    const float* __restrict__ bias, ushort* __restrict__ Qo,
    ushort* __restrict__ Ko, ushort* __restrict__ Vto,
    float* __restrict__ outF, const float* __restrict__ resid,
    int N, int K) {
  __shared__ ushort Al[128 * 32];
  __shared__ ushort Bl[128 * 32];
  const int tid = threadIdx.x;
  const int w = tid >> 6, l = tid & 63;
  const int cc = l & 15, gg = l >> 4;
  const int bm = blockIdx.y * 128, bn = blockIdx.x * 128;
  const int wr = w >> 1, wc = w & 1;
  f32x4 acc[4][4] = {};

  for (int k0 = 0; k0 < K; k0 += 32) {
#pragma unroll
    for (int q = 0; q < 2; ++q) {
      const int cbase = q * 256 + w * 64;
      const int c = cbase + l;
      gload_lds16(A + (size_t)(bm + (c >> 2)) * K + k0 + (c & 3) * 8,
                  &Al[cbase * 8]);
      gload_lds16(Bt + (size_t)(bn + (c >> 2)) * K + k0 + (c & 3) * 8,
                  &Bl[cbase * 8]);
    }
    __syncthreads();
    bf16x8 aF[4], bF[4];
#pragma unroll
    for (int i = 0; i < 4; ++i)
      aF[i] = *reinterpret_cast<const bf16x8*>(
          &Al[(wr * 64 + i * 16 + cc) * 32 + gg * 8]);
#pragma unroll
    for (int j = 0; j < 4; ++j)
      bF[j] = *reinterpret_cast<const bf16x8*>(
          &Bl[(wc * 64 + j * 16 + cc) * 32 + gg * 8]);
#pragma unroll
    for (int i = 0; i < 4; ++i)
#pragma unroll
      for (int j = 0; j < 4; ++j)
        acc[i][j] = __builtin_amdgcn_mfma_f32_16x16x32_bf16(aF[i], bF[j],
                                                            acc[i][j], 0, 0, 0);
    __syncthreads();
  }

  if (EPI == 0) {
#pragma unroll
    for (int j = 0; j < 4; ++j) {
      const int colbase = bn + wc * 64 + j * 16;
      const int h = colbase / 192, rem = colbase % 192;
      const int type = rem / 64, d = (rem % 64) + cc;
      const float bv = bias[colbase + cc];
#pragma unroll
      for (int i = 0; i < 4; ++i) {
        const int rowbase = bm + wr * 64 + i * 16 + 4 * gg;
        const int b = rowbase >> 11, ll = rowbase & 2047;
        if (type < 2) {
          ushort* dst = (type == 0) ? Qo : Ko;
#pragma unroll
          for (int r = 0; r < 4; ++r)
            dst[((size_t)(b * H_N + h) * L_SEQ + ll + r) * DK + d] =
                f2bf(acc[i][j][r] + bv);
        } else {
          ushort4 pk;
          pk.x = f2bf(acc[i][j][0] + bv);
          pk.y = f2bf(acc[i][j][1] + bv);
          pk.z = f2bf(acc[i][j][2] + bv);
          pk.w = f2bf(acc[i][j][3] + bv);
          *reinterpret_cast<ushort4*>(
              &Vto[((size_t)(b * H_N + h) * DK + d) * L_SEQ + ll]) = pk;
        }
      }
    }
  } else {
#pragma unroll
    for (int j = 0; j < 4; ++j) {
      const int col = bn + wc * 64 + j * 16 + cc;
      const float bv = bias[col];
#pragma unroll
      for (int i = 0; i < 4; ++i) {
        const int rowbase = bm + wr * 64 + i * 16 + 4 * gg;
#pragma unroll
        for (int r = 0; r < 4; ++r) {
          const size_t off = (size_t)(rowbase + r) * N + col;
          outF[off] = acc[i][j][r] + bv + resid[off];
        }
      }
    }
  }
}

// ---------------------------------------------- attention core (bf16 MFMA)
// 1-D grid of 512 blocks x 512 thr (8 waves). id&7 = XCD (HW round-robins
// consecutive ids across XCDs) -> each XCD owns 4 (b,h) pairs => K/V 2MB,
// L2-resident. Waves 0-3: q-tile (31-pair); waves 4-7: q-tile (pair) =>
// uniform 33 tile-iters per block (causal balance).
__global__ __launch_bounds__(512) void attn_mfma(
    const ushort* __restrict__ Q, const ushort* __restrict__ K,
    const ushort* __restrict__ Vt, ushort* __restrict__ attn_out) {
  __shared__ ushort P_lds[8][16][72];
  const int id = blockIdx.x;
  const int xcd = id & 7, jj = id >> 3;        // jj in [0,64)
  const int bh = xcd + 8 * (jj >> 4);          // 4 bh per XCD
  const int pair = jj & 15;                    // 0..15
  const int tid = threadIdx.x;
  const int w = tid >> 6, lane = tid & 63;
  const int qt = (w < 4) ? (31 - pair) : pair;
  const int c = lane & 15, g = lane >> 4;
  const int b = bh >> 3, h = bh & 7;
  const size_t qk_base = (size_t)bh * L_SEQ * DK;
  const size_t vt_base = (size_t)bh * DK * L_SEQ;
  const int q0 = qt * 64 + (w & 3) * 16;

  bf16x8 qA[2];
  {
    const ushort* qp = Q + qk_base + (size_t)(q0 + c) * DK + g * 8;
    qA[0] = *reinterpret_cast<const bf16x8*>(qp);
    qA[1] = *reinterpret_cast<const bf16x8*>(qp + 32);
  }

  f32x4 O[4] = {};
  float mrow[4] = {-INFINITY, -INFINITY, -INFINITY, -INFINITY};
  float lrow[4] = {};
  const f32x4 zero4 = {0.f, 0.f, 0.f, 0.f};

  for (int jt = 0; jt <= qt; ++jt) {
    const int j0 = jt * 64;
    f32x4 S[4];
    __builtin_amdgcn_s_setprio(1);
#pragma unroll
    for (int n = 0; n < 4; ++n) {
      const ushort* kp = K + qk_base + (size_t)(j0 + n * 16 + c) * DK + g * 8;
      bf16x8 kb0 = *reinterpret_cast<const bf16x8*>(kp);
      bf16x8 kb1 = *reinterpret_cast<const bf16x8*>(kp + 32);
      S[n] = __builtin_amdgcn_mfma_f32_16x16x32_bf16(qA[0], kb0, zero4, 0, 0, 0);
      S[n] = __builtin_amdgcn_mfma_f32_16x16x32_bf16(qA[1], kb1, S[n], 0, 0, 0);
    }
    __builtin_amdgcn_s_setprio(0);
    bf16x8 vb[4][2];
#pragma unroll
    for (int t = 0; t < 4; ++t) {
      const ushort* vp = Vt + vt_base + (size_t)(t * 16 + c) * L_SEQ + j0 + g * 8;
      vb[t][0] = *reinterpret_cast<const bf16x8*>(vp);
      vb[t][1] = *reinterpret_cast<const bf16x8*>(vp + 32);
    }
    const bool diag = (jt == qt);
    float corr[4];
#pragma unroll
    for (int n = 0; n < 4; ++n)
#pragma unroll
      for (int r = 0; r < 4; ++r) {
        float v = S[n][r] * SCALE;
        if (diag && (j0 + n * 16 + c) > (q0 + 4 * g + r)) v = -INFINITY;
        S[n][r] = v;
      }
#pragma unroll
    for (int r = 0; r < 4; ++r) {
      float pm = fmaxf(fmaxf(S[0][r], S[1][r]), fmaxf(S[2][r], S[3][r]));
      pm = fmaxf(pm, __shfl_xor(pm, 1, 16));
      pm = fmaxf(pm, __shfl_xor(pm, 2, 16));
      pm = fmaxf(pm, __shfl_xor(pm, 4, 16));
      pm = fmaxf(pm, __shfl_xor(pm, 8, 16));
      const float mnew = fmaxf(mrow[r], pm);
      corr[r] = __expf(mrow[r] - mnew);
      float s = 0.f;
#pragma unroll
      for (int n = 0; n < 4; ++n) {
        const float p = __expf(S[n][r] - mnew);
        S[n][r] = p;
        s += p;
      }
      s += __shfl_xor(s, 1, 16);
      s += __shfl_xor(s, 2, 16);
      s += __shfl_xor(s, 4, 16);
      s += __shfl_xor(s, 8, 16);
      lrow[r] = lrow[r] * corr[r] + s;
      mrow[r] = mnew;
    }
#pragma unroll
    for (int n = 0; n < 4; ++n)
#pragma unroll
      for (int r = 0; r < 4; ++r)
        P_lds[w][4 * g + r][n * 16 + c] = f2bf(S[n][r]);
    bf16x8 pA0 = *reinterpret_cast<const bf16x8*>(&P_lds[w][c][g * 8]);
    bf16x8 pA1 = *reinterpret_cast<const bf16x8*>(&P_lds[w][c][32 + g * 8]);
#pragma unroll
    for (int t = 0; t < 4; ++t)
#pragma unroll
      for (int r = 0; r < 4; ++r) O[t][r] *= corr[r];
    __builtin_amdgcn_s_setprio(1);
#pragma unroll
    for (int t = 0; t < 4; ++t) {
      O[t] = __builtin_amdgcn_mfma_f32_16x16x32_bf16(pA0, vb[t][0], O[t], 0, 0, 0);
      O[t] = __builtin_amdgcn_mfma_f32_16x16x32_bf16(pA1, vb[t][1], O[t], 0, 0, 0);
    }
    __builtin_amdgcn_s_setprio(0);
  }
  float inv[4];
#pragma unroll
  for (int r = 0; r < 4; ++r) inv[r] = 1.f / lrow[r];
#pragma unroll
  for (int t = 0; t < 4; ++t)
#pragma unroll
    for (int r = 0; r < 4; ++r)
      attn_out[((size_t)b * L_SEQ + q0 + 4 * g + r) * C_DIM + h * DK + t * 16 + c] =
          f2bf(O[t][r] * inv[r]);
}

// ------------------------------------------------------------------- launch
extern "C" void kernel_launch(void* const* d_in, const int* in_sizes, int n_in,
                              void* d_out, int out_size, void* d_ws,
                              size_t ws_size, hipStream_t stream) {
  const float* x     = (const float*)d_in[0];
  const float* W_in  = (const float*)d_in[1];
  const float* b_in  = (const float*)d_in[2];
  const float* W_out = (const float*)d_in[3];
  const float* b_out = (const float*)d_in[4];
  float* out = (float*)d_out;

  ushort* xbf   = (ushort*)d_ws;                       // 8192x512
  ushort* WinT  = xbf + (size_t)M_ROWS * C_DIM;        // 1536x512
  ushort* WoutT = WinT + (size_t)N_QKV * C_DIM;        // 512x512
  ushort* Qo    = WoutT + (size_t)C_DIM * C_DIM;       // [BH,L,64]
  ushort* Ko    = Qo + (size_t)M_ROWS * C_DIM;
  ushort* Vto   = Ko + (size_t)M_ROWS * C_DIM;         // [BH,64,L]
  ushort* attnb = Vto + (size_t)M_ROWS * C_DIM;        // [8192,512]

  convert_bf16<<<(M_ROWS * C_DIM / 4 + 255) / 256, 256, 0, stream>>>(
      x, xbf, M_ROWS * C_DIM / 4);
  transpose_bf16<<<dim3(N_QKV / 64, C_DIM / 64), 256, 0, stream>>>(
      W_in, WinT, C_DIM, N_QKV);
  transpose_bf16<<<dim3(C_DIM / 64, C_DIM / 64), 256, 0, stream>>>(
      W_out, WoutT, C_DIM, C_DIM);

  gemm_bf16<0><<<dim3(N_QKV / 128, M_ROWS / 128), 256, 0, stream>>>(
      xbf, WinT, b_in, Qo, Ko, Vto, nullptr, nullptr, N_QKV, C_DIM);
  attn_mfma<<<dim3(512, 1, 1), 512, 0, stream>>>(Qo, Ko, Vto, attnb);
  gemm_bf16<1><<<dim3(C_DIM / 128, M_ROWS / 128), 256, 0, stream>>>(
      attnb, WoutT, b_out, nullptr, nullptr, nullptr, out, x, C_DIM, C_DIM);
}